// Round 1
// baseline (2240.424 us; speedup 1.0000x reference)
//
#include <hip/hip_runtime.h>
#include <cstddef>
#include <math.h>

#define N_NODES 50000
#define N_EDGES 1600000
#define IN_C 512
#define HID_C 256
#define OUT_C 50
#define NUM_LAYERS 10

// ---------------------------------------------------------------------------
// GEMM1: C[M,256] = relu(A[M,512] @ W1[512,256] + b1), fp32, 64x64 tile, BK=16
// ---------------------------------------------------------------------------
__global__ __launch_bounds__(256) void gemm1_relu(const float* __restrict__ A,
                                                  const float* __restrict__ W,
                                                  const float* __restrict__ bias,
                                                  float* __restrict__ C) {
    __shared__ float As[16][68];   // [k][m], pad to 68 for 16B-aligned rows
    __shared__ float Bs[16][64];   // [k][n]
    const int tid = threadIdx.x;
    const int tx = tid & 15;       // n-quad
    const int ty = tid >> 4;       // m-quad
    const int m0 = blockIdx.x * 64;
    const int n0 = blockIdx.y * 64;

    float acc[4][4];
#pragma unroll
    for (int i = 0; i < 4; ++i)
#pragma unroll
        for (int j = 0; j < 4; ++j) acc[i][j] = 0.f;

    const int arow = tid >> 2;          // 0..63
    const int akk  = (tid & 3) << 2;    // 0,4,8,12
    const int brow = tid >> 4;          // 0..15
    const int bcol = (tid & 15) << 2;   // 0..60

    for (int k0 = 0; k0 < IN_C; k0 += 16) {
        // stage A tile (64 rows x 16 k)
        float4 av = make_float4(0.f, 0.f, 0.f, 0.f);
        int gr = m0 + arow;
        if (gr < N_NODES)
            av = *(const float4*)(A + (size_t)gr * IN_C + k0 + akk);
        As[akk + 0][arow] = av.x;
        As[akk + 1][arow] = av.y;
        As[akk + 2][arow] = av.z;
        As[akk + 3][arow] = av.w;
        // stage B tile (16 k x 64 n)
        float4 bv = *(const float4*)(W + (size_t)(k0 + brow) * HID_C + n0 + bcol);
        *(float4*)&Bs[brow][bcol] = bv;
        __syncthreads();

#pragma unroll
        for (int kk = 0; kk < 16; ++kk) {
            float a[4], b[4];
#pragma unroll
            for (int i = 0; i < 4; ++i) a[i] = As[kk][ty * 4 + i];
#pragma unroll
            for (int j = 0; j < 4; ++j) b[j] = Bs[kk][tx * 4 + j];
#pragma unroll
            for (int i = 0; i < 4; ++i)
#pragma unroll
                for (int j = 0; j < 4; ++j) acc[i][j] = fmaf(a[i], b[j], acc[i][j]);
        }
        __syncthreads();
    }

#pragma unroll
    for (int i = 0; i < 4; ++i) {
        int r = m0 + ty * 4 + i;
        if (r >= N_NODES) continue;
#pragma unroll
        for (int j = 0; j < 4; ++j) {
            int c = n0 + tx * 4 + j;
            float v = acc[i][j] + bias[c];
            C[(size_t)r * HID_C + c] = v > 0.f ? v : 0.f;
        }
    }
}

// ---------------------------------------------------------------------------
// GEMM2: out[M,50] = H[M,256] @ W2[256,50] + b2.  One wave per node, W2 in LDS.
// ---------------------------------------------------------------------------
__global__ __launch_bounds__(256) void gemm2(const float* __restrict__ H,
                                             const float* __restrict__ W2,
                                             const float* __restrict__ b2,
                                             float* __restrict__ out) {
    __shared__ float Ws[HID_C * OUT_C + 64];  // +64 so lanes 50..63 stay in-bounds
    __shared__ float bs[64];
    for (int i = threadIdx.x; i < HID_C * OUT_C; i += blockDim.x) Ws[i] = W2[i];
    for (int i = HID_C * OUT_C + threadIdx.x; i < HID_C * OUT_C + 64; i += blockDim.x) Ws[i] = 0.f;
    if (threadIdx.x < 64) bs[threadIdx.x] = (threadIdx.x < OUT_C) ? b2[threadIdx.x] : 0.f;
    __syncthreads();

    const int wave = threadIdx.x >> 6;
    const int lane = threadIdx.x & 63;
    const int wpb = blockDim.x >> 6;

    for (int node = blockIdx.x * wpb + wave; node < N_NODES; node += gridDim.x * wpb) {
        const float* hrow = H + (size_t)node * HID_C;
        float acc = bs[lane];
#pragma unroll 4
        for (int k = 0; k < HID_C; ++k) {
            acc = fmaf(hrow[k], Ws[k * OUT_C + lane], acc);
        }
        if (lane < OUT_C) out[(size_t)node * OUT_C + lane] = acc;
    }
}

// ---------------------------------------------------------------------------
// CSR build
// ---------------------------------------------------------------------------
__global__ void hist_kernel(const int* __restrict__ row, int* __restrict__ cnt) {
    int e = blockIdx.x * blockDim.x + threadIdx.x;
    if (e < N_EDGES) atomicAdd(&cnt[row[e]], 1);
}

__global__ __launch_bounds__(1024) void scan_kernel(const int* __restrict__ cnt,
                                                    int* __restrict__ rowptr) {
    __shared__ int sd[1024];
    __shared__ int soff;
    if (threadIdx.x == 0) soff = 0;
    __syncthreads();
    for (int base = 0; base < N_NODES; base += 1024) {
        int i = base + threadIdx.x;
        int v = (i < N_NODES) ? cnt[i] : 0;
        sd[threadIdx.x] = v;
        __syncthreads();
        for (int off = 1; off < 1024; off <<= 1) {
            int t = (threadIdx.x >= off) ? sd[threadIdx.x - off] : 0;
            __syncthreads();
            sd[threadIdx.x] += t;
            __syncthreads();
        }
        int excl = sd[threadIdx.x] - v;
        int total = sd[1023];
        int off0 = soff;
        if (i < N_NODES) rowptr[i] = off0 + excl;
        __syncthreads();
        if (threadIdx.x == 0) soff = off0 + total;
        __syncthreads();
    }
    if (threadIdx.x == 0) rowptr[N_NODES] = soff;
}

__global__ void scatter_kernel(const int* __restrict__ row, const int* __restrict__ col,
                               const float* __restrict__ w, const int* __restrict__ rowptr,
                               int* __restrict__ fill, int* __restrict__ cols_s,
                               float* __restrict__ ws_s) {
    int e = blockIdx.x * blockDim.x + threadIdx.x;
    if (e >= N_EDGES) return;
    int r = row[e];
    int pos = rowptr[r] + atomicAdd(&fill[r], 1);
    cols_s[pos] = col[e];
    ws_s[pos] = w[e];
}

// ---------------------------------------------------------------------------
// Propagation: hout[i,c] = 0.9 * sum_e w[e]*hin[col[e],c] + 0.1 * h0[i,c]
// one wave per node, lane = channel
// ---------------------------------------------------------------------------
__global__ __launch_bounds__(256) void prop_kernel(const int* __restrict__ rowptr,
                                                   const int* __restrict__ cols,
                                                   const float* __restrict__ wv,
                                                   const float* __restrict__ hin,
                                                   const float* __restrict__ h0,
                                                   float* __restrict__ hout) {
    int wave = (blockIdx.x * blockDim.x + threadIdx.x) >> 6;
    int lane = threadIdx.x & 63;
    if (wave >= N_NODES) return;
    int s = rowptr[wave];
    int e = rowptr[wave + 1];
    int c = (lane < OUT_C) ? lane : 0;   // keep lanes 50..63 in-bounds, branch-free loop
    float acc = 0.f;
    for (int i = s; i < e; ++i) {
        int src = cols[i];
        float w = wv[i];
        acc = fmaf(w, hin[(size_t)src * OUT_C + c], acc);
    }
    if (lane < OUT_C) {
        size_t o = (size_t)wave * OUT_C + lane;
        hout[o] = 0.9f * acc + 0.1f * h0[o];
    }
}

// ---------------------------------------------------------------------------
// log_softmax over 50 channels, one wave per node
// ---------------------------------------------------------------------------
__global__ __launch_bounds__(256) void logsoftmax_kernel(const float* __restrict__ h,
                                                         float* __restrict__ out) {
    int wave = (blockIdx.x * blockDim.x + threadIdx.x) >> 6;
    int lane = threadIdx.x & 63;
    if (wave >= N_NODES) return;
    float v = (lane < OUT_C) ? h[(size_t)wave * OUT_C + lane] : -INFINITY;
    float m = v;
#pragma unroll
    for (int off = 32; off; off >>= 1) m = fmaxf(m, __shfl_xor(m, off, 64));
    float p = (lane < OUT_C) ? __expf(v - m) : 0.f;
    float ssum = p;
#pragma unroll
    for (int off = 32; off; off >>= 1) ssum += __shfl_xor(ssum, off, 64);
    if (lane < OUT_C) out[(size_t)wave * OUT_C + lane] = (v - m) - __logf(ssum);
}

// ---------------------------------------------------------------------------
extern "C" void kernel_launch(void* const* d_in, const int* in_sizes, int n_in,
                              void* d_out, int out_size, void* d_ws, size_t ws_size,
                              hipStream_t stream) {
    const float* x    = (const float*)d_in[0];
    const int*   erow = (const int*)d_in[1];
    const int*   ecol = (const int*)d_in[2];
    const float* ew   = (const float*)d_in[3];
    const float* W1   = (const float*)d_in[4];
    const float* b1   = (const float*)d_in[5];
    const float* W2   = (const float*)d_in[6];
    const float* b2   = (const float*)d_in[7];
    float* out = (float*)d_out;

    char* p = (char*)d_ws;
    auto alloc = [&](size_t bytes) {
        char* r = p;
        p += (bytes + 255) & ~(size_t)255;
        return r;
    };
    float* h_hid  = (float*)alloc((size_t)N_NODES * HID_C * 4);
    float* h0     = (float*)alloc((size_t)N_NODES * OUT_C * 4);
    float* ha     = (float*)alloc((size_t)N_NODES * OUT_C * 4);
    float* hb     = (float*)alloc((size_t)N_NODES * OUT_C * 4);
    int*   cols_s = (int*)alloc((size_t)N_EDGES * 4);
    float* ws_s   = (float*)alloc((size_t)N_EDGES * 4);
    int*   rowptr = (int*)alloc((size_t)(N_NODES + 1) * 4);
    int*   cnt    = (int*)alloc((size_t)N_NODES * 4);
    int*   fill   = (int*)alloc((size_t)N_NODES * 4);  // contiguous with cnt

    // zero cnt + fill (adjacent allocations, but alloc pads — memset both)
    hipMemsetAsync(cnt, 0, (size_t)N_NODES * 4, stream);
    hipMemsetAsync(fill, 0, (size_t)N_NODES * 4, stream);

    // CSR build
    hist_kernel<<<(N_EDGES + 255) / 256, 256, 0, stream>>>(erow, cnt);
    scan_kernel<<<1, 1024, 0, stream>>>(cnt, rowptr);
    scatter_kernel<<<(N_EDGES + 255) / 256, 256, 0, stream>>>(erow, ecol, ew, rowptr,
                                                              fill, cols_s, ws_s);

    // MLP
    dim3 g1((N_NODES + 63) / 64, HID_C / 64);
    gemm1_relu<<<g1, 256, 0, stream>>>(x, W1, b1, h_hid);
    gemm2<<<2500, 256, 0, stream>>>(h_hid, W2, b2, h0);

    // Propagation x10 (ping-pong)
    const int prop_blocks = (N_NODES * 64 + 255) / 256;
    const float* cur = h0;
    float* nxt = ha;
    for (int l = 0; l < NUM_LAYERS; ++l) {
        prop_kernel<<<prop_blocks, 256, 0, stream>>>(rowptr, cols_s, ws_s, cur, h0, nxt);
        const float* t = nxt;
        nxt = (nxt == ha) ? hb : ha;
        cur = t;
    }

    // log_softmax
    logsoftmax_kernel<<<prop_blocks, 256, 0, stream>>>(cur, out);
}

// Round 2
// 1115.317 us; speedup vs baseline: 2.0088x; 2.0088x over previous
//
#include <hip/hip_runtime.h>
#include <cstddef>
#include <math.h>

#define N_NODES 50000
#define N_EDGES 1600000
#define IN_C 512
#define HID_C 256
#define OUT_C 50
#define PAD_C 64          // padded channel stride for h (256 B rows)
#define NUM_LAYERS 10
#define NBLK 196          // ceil(50000/256)

// ---------------------------------------------------------------------------
// GEMM1: C[M,256] = relu(A[M,512] @ W1[512,256] + b1), fp32, 64x64 tile, BK=16
// ---------------------------------------------------------------------------
__global__ __launch_bounds__(256) void gemm1_relu(const float* __restrict__ A,
                                                  const float* __restrict__ W,
                                                  const float* __restrict__ bias,
                                                  float* __restrict__ C) {
    __shared__ float As[16][68];
    __shared__ float Bs[16][64];
    const int tid = threadIdx.x;
    const int tx = tid & 15;
    const int ty = tid >> 4;
    const int m0 = blockIdx.x * 64;
    const int n0 = blockIdx.y * 64;

    float acc[4][4];
#pragma unroll
    for (int i = 0; i < 4; ++i)
#pragma unroll
        for (int j = 0; j < 4; ++j) acc[i][j] = 0.f;

    const int arow = tid >> 2;
    const int akk  = (tid & 3) << 2;
    const int brow = tid >> 4;
    const int bcol = (tid & 15) << 2;

    for (int k0 = 0; k0 < IN_C; k0 += 16) {
        float4 av = make_float4(0.f, 0.f, 0.f, 0.f);
        int gr = m0 + arow;
        if (gr < N_NODES)
            av = *(const float4*)(A + (size_t)gr * IN_C + k0 + akk);
        As[akk + 0][arow] = av.x;
        As[akk + 1][arow] = av.y;
        As[akk + 2][arow] = av.z;
        As[akk + 3][arow] = av.w;
        float4 bv = *(const float4*)(W + (size_t)(k0 + brow) * HID_C + n0 + bcol);
        *(float4*)&Bs[brow][bcol] = bv;
        __syncthreads();

#pragma unroll
        for (int kk = 0; kk < 16; ++kk) {
            float a[4], b[4];
#pragma unroll
            for (int i = 0; i < 4; ++i) a[i] = As[kk][ty * 4 + i];
#pragma unroll
            for (int j = 0; j < 4; ++j) b[j] = Bs[kk][tx * 4 + j];
#pragma unroll
            for (int i = 0; i < 4; ++i)
#pragma unroll
                for (int j = 0; j < 4; ++j) acc[i][j] = fmaf(a[i], b[j], acc[i][j]);
        }
        __syncthreads();
    }

#pragma unroll
    for (int i = 0; i < 4; ++i) {
        int r = m0 + ty * 4 + i;
        if (r >= N_NODES) continue;
#pragma unroll
        for (int j = 0; j < 4; ++j) {
            int c = n0 + tx * 4 + j;
            float v = acc[i][j] + bias[c];
            C[(size_t)r * HID_C + c] = v > 0.f ? v : 0.f;
        }
    }
}

// ---------------------------------------------------------------------------
// pad W2 [256,50] -> Wp [256,64] (zeros), b2 -> bp[64]
// ---------------------------------------------------------------------------
__global__ void pad_w2(const float* __restrict__ W2, const float* __restrict__ b2,
                       float* __restrict__ Wp, float* __restrict__ bp) {
    int idx = blockIdx.x * blockDim.x + threadIdx.x;
    if (idx < HID_C * PAD_C) {
        int k = idx >> 6, j = idx & 63;
        Wp[idx] = (j < OUT_C) ? W2[k * OUT_C + j] : 0.f;
    }
    if (idx < PAD_C) bp[idx] = (idx < OUT_C) ? b2[idx] : 0.f;
}

// ---------------------------------------------------------------------------
// GEMM2 tiled: h0[M,64pad] = H[M,256] @ Wp[256,64] + bp   (pad cols -> 0)
// ---------------------------------------------------------------------------
__global__ __launch_bounds__(256) void gemm2_tiled(const float* __restrict__ H,
                                                   const float* __restrict__ Wp,
                                                   const float* __restrict__ bp,
                                                   float* __restrict__ h0) {
    __shared__ float As[16][68];
    __shared__ float Bs[16][64];
    const int tid = threadIdx.x;
    const int tx = tid & 15;
    const int ty = tid >> 4;
    const int m0 = blockIdx.x * 64;

    float acc[4][4];
#pragma unroll
    for (int i = 0; i < 4; ++i)
#pragma unroll
        for (int j = 0; j < 4; ++j) acc[i][j] = 0.f;

    const int arow = tid >> 2;
    const int akk  = (tid & 3) << 2;
    const int brow = tid >> 4;
    const int bcol = (tid & 15) << 2;

    for (int k0 = 0; k0 < HID_C; k0 += 16) {
        float4 av = make_float4(0.f, 0.f, 0.f, 0.f);
        int gr = m0 + arow;
        if (gr < N_NODES)
            av = *(const float4*)(H + (size_t)gr * HID_C + k0 + akk);
        As[akk + 0][arow] = av.x;
        As[akk + 1][arow] = av.y;
        As[akk + 2][arow] = av.z;
        As[akk + 3][arow] = av.w;
        float4 bv = *(const float4*)(Wp + (size_t)(k0 + brow) * PAD_C + bcol);
        *(float4*)&Bs[brow][bcol] = bv;
        __syncthreads();

#pragma unroll
        for (int kk = 0; kk < 16; ++kk) {
            float a[4], b[4];
#pragma unroll
            for (int i = 0; i < 4; ++i) a[i] = As[kk][ty * 4 + i];
#pragma unroll
            for (int j = 0; j < 4; ++j) b[j] = Bs[kk][tx * 4 + j];
#pragma unroll
            for (int i = 0; i < 4; ++i)
#pragma unroll
                for (int j = 0; j < 4; ++j) acc[i][j] = fmaf(a[i], b[j], acc[i][j]);
        }
        __syncthreads();
    }

#pragma unroll
    for (int i = 0; i < 4; ++i) {
        int r = m0 + ty * 4 + i;
        if (r >= N_NODES) continue;
#pragma unroll
        for (int j = 0; j < 4; ++j) {
            int c = tx * 4 + j;
            h0[(size_t)r * PAD_C + c] = acc[i][j] + bp[c];
        }
    }
}

// ---------------------------------------------------------------------------
// CSR build: histogram + 3-kernel scan + scatter
// ---------------------------------------------------------------------------
__global__ void hist_kernel(const int* __restrict__ row, int* __restrict__ cnt) {
    int e = blockIdx.x * blockDim.x + threadIdx.x;
    if (e < N_EDGES) atomicAdd(&cnt[row[e]], 1);
}

__global__ __launch_bounds__(256) void scan1(const int* __restrict__ cnt,
                                             int* __restrict__ rowptr,
                                             int* __restrict__ bsum) {
    __shared__ int sd[256];
    int i = blockIdx.x * 256 + threadIdx.x;
    int v = (i < N_NODES) ? cnt[i] : 0;
    sd[threadIdx.x] = v;
    __syncthreads();
    for (int off = 1; off < 256; off <<= 1) {
        int t = (threadIdx.x >= off) ? sd[threadIdx.x - off] : 0;
        __syncthreads();
        sd[threadIdx.x] += t;
        __syncthreads();
    }
    if (i < N_NODES) rowptr[i] = sd[threadIdx.x] - v;   // block-local exclusive
    if (threadIdx.x == 255) bsum[blockIdx.x] = sd[255];
}

__global__ __launch_bounds__(256) void scan2(const int* __restrict__ bsum,
                                             int* __restrict__ boff,
                                             int* __restrict__ total_out) {
    __shared__ int sd[256];
    int v = (threadIdx.x < NBLK) ? bsum[threadIdx.x] : 0;
    sd[threadIdx.x] = v;
    __syncthreads();
    for (int off = 1; off < 256; off <<= 1) {
        int t = (threadIdx.x >= off) ? sd[threadIdx.x - off] : 0;
        __syncthreads();
        sd[threadIdx.x] += t;
        __syncthreads();
    }
    if (threadIdx.x < NBLK) boff[threadIdx.x] = sd[threadIdx.x] - v;
    if (threadIdx.x == 255) total_out[0] = sd[255];
}

__global__ void scan3(int* __restrict__ rowptr, const int* __restrict__ boff) {
    int i = blockIdx.x * blockDim.x + threadIdx.x;
    if (i < N_NODES) rowptr[i] += boff[blockIdx.x];
}

__global__ void scatter_kernel(const int* __restrict__ row, const int* __restrict__ col,
                               const float* __restrict__ w, const int* __restrict__ rowptr,
                               int* __restrict__ fill, int* __restrict__ cols_s,
                               float* __restrict__ ws_s) {
    int e = blockIdx.x * blockDim.x + threadIdx.x;
    if (e >= N_EDGES) return;
    int r = row[e];
    int pos = rowptr[r] + atomicAdd(&fill[r], 1);
    cols_s[pos] = col[e];
    ws_s[pos] = w[e];
}

// ---------------------------------------------------------------------------
// Propagation (padded h, stride 64): one wave per node, lane = channel,
// edge loop unrolled x8 with independent accumulators for latency hiding.
// ---------------------------------------------------------------------------
__global__ __launch_bounds__(256) void prop_kernel(const int* __restrict__ rowptr,
                                                   const int* __restrict__ cols,
                                                   const float* __restrict__ wv,
                                                   const float* __restrict__ hin,
                                                   const float* __restrict__ h0,
                                                   float* __restrict__ hout) {
    int wave = (blockIdx.x * blockDim.x + threadIdx.x) >> 6;
    int lane = threadIdx.x & 63;
    if (wave >= N_NODES) return;
    int s = rowptr[wave];
    int e = rowptr[wave + 1];
    float a0 = 0.f, a1 = 0.f, a2 = 0.f, a3 = 0.f;
    float a4 = 0.f, a5 = 0.f, a6 = 0.f, a7 = 0.f;
    int i = s;
    for (; i + 8 <= e; i += 8) {
        int s0 = cols[i + 0], s1 = cols[i + 1], s2 = cols[i + 2], s3 = cols[i + 3];
        int s4 = cols[i + 4], s5 = cols[i + 5], s6 = cols[i + 6], s7 = cols[i + 7];
        float w0 = wv[i + 0], w1 = wv[i + 1], w2 = wv[i + 2], w3 = wv[i + 3];
        float w4 = wv[i + 4], w5 = wv[i + 5], w6 = wv[i + 6], w7 = wv[i + 7];
        a0 = fmaf(w0, hin[(size_t)s0 * PAD_C + lane], a0);
        a1 = fmaf(w1, hin[(size_t)s1 * PAD_C + lane], a1);
        a2 = fmaf(w2, hin[(size_t)s2 * PAD_C + lane], a2);
        a3 = fmaf(w3, hin[(size_t)s3 * PAD_C + lane], a3);
        a4 = fmaf(w4, hin[(size_t)s4 * PAD_C + lane], a4);
        a5 = fmaf(w5, hin[(size_t)s5 * PAD_C + lane], a5);
        a6 = fmaf(w6, hin[(size_t)s6 * PAD_C + lane], a6);
        a7 = fmaf(w7, hin[(size_t)s7 * PAD_C + lane], a7);
    }
    for (; i < e; ++i)
        a0 = fmaf(wv[i], hin[(size_t)cols[i] * PAD_C + lane], a0);
    float acc = ((a0 + a1) + (a2 + a3)) + ((a4 + a5) + (a6 + a7));
    size_t o = (size_t)wave * PAD_C + lane;
    hout[o] = 0.9f * acc + 0.1f * h0[o];
}

// ---------------------------------------------------------------------------
// log_softmax over 50 channels (padded input stride 64), one wave per node
// ---------------------------------------------------------------------------
__global__ __launch_bounds__(256) void logsoftmax_kernel(const float* __restrict__ h,
                                                         float* __restrict__ out) {
    int wave = (blockIdx.x * blockDim.x + threadIdx.x) >> 6;
    int lane = threadIdx.x & 63;
    if (wave >= N_NODES) return;
    float v = (lane < OUT_C) ? h[(size_t)wave * PAD_C + lane] : -INFINITY;
    float m = v;
#pragma unroll
    for (int off = 32; off; off >>= 1) m = fmaxf(m, __shfl_xor(m, off, 64));
    float p = (lane < OUT_C) ? __expf(v - m) : 0.f;
    float ssum = p;
#pragma unroll
    for (int off = 32; off; off >>= 1) ssum += __shfl_xor(ssum, off, 64);
    if (lane < OUT_C) out[(size_t)wave * OUT_C + lane] = (v - m) - __logf(ssum);
}

// ---------------------------------------------------------------------------
extern "C" void kernel_launch(void* const* d_in, const int* in_sizes, int n_in,
                              void* d_out, int out_size, void* d_ws, size_t ws_size,
                              hipStream_t stream) {
    const float* x    = (const float*)d_in[0];
    const int*   erow = (const int*)d_in[1];
    const int*   ecol = (const int*)d_in[2];
    const float* ew   = (const float*)d_in[3];
    const float* W1   = (const float*)d_in[4];
    const float* b1   = (const float*)d_in[5];
    const float* W2   = (const float*)d_in[6];
    const float* b2   = (const float*)d_in[7];
    float* out = (float*)d_out;

    char* p = (char*)d_ws;
    auto alloc = [&](size_t bytes) {
        char* r = p;
        p += (bytes + 255) & ~(size_t)255;
        return r;
    };
    float* h_hid  = (float*)alloc((size_t)N_NODES * HID_C * 4);   // 51.2 MB
    float* h0     = (float*)alloc((size_t)N_NODES * PAD_C * 4);   // 12.8 MB
    int*   cols_s = (int*)alloc((size_t)N_EDGES * 4);
    float* ws_s   = (float*)alloc((size_t)N_EDGES * 4);
    int*   rowptr = (int*)alloc((size_t)(N_NODES + 1) * 4);
    int*   cnt    = (int*)alloc((size_t)N_NODES * 4);
    int*   fill   = (int*)alloc((size_t)N_NODES * 4);
    int*   bsum   = (int*)alloc((size_t)NBLK * 4);
    int*   boff   = (int*)alloc((size_t)NBLK * 4);
    float* Wp     = (float*)alloc((size_t)HID_C * PAD_C * 4);
    float* bp     = (float*)alloc((size_t)PAD_C * 4);
    // ha/hb alias h_hid: h_hid is dead after gemm2_tiled reads it
    float* ha = h_hid;
    float* hb = h_hid + (size_t)N_NODES * PAD_C;

    hipMemsetAsync(cnt, 0, (size_t)N_NODES * 4, stream);
    hipMemsetAsync(fill, 0, (size_t)N_NODES * 4, stream);

    // CSR build
    hist_kernel<<<(N_EDGES + 255) / 256, 256, 0, stream>>>(erow, cnt);
    scan1<<<NBLK, 256, 0, stream>>>(cnt, rowptr, bsum);
    scan2<<<1, 256, 0, stream>>>(bsum, boff, rowptr + N_NODES);
    scan3<<<NBLK, 256, 0, stream>>>(rowptr, boff);
    scatter_kernel<<<(N_EDGES + 255) / 256, 256, 0, stream>>>(erow, ecol, ew, rowptr,
                                                              fill, cols_s, ws_s);

    // MLP
    dim3 g1((N_NODES + 63) / 64, HID_C / 64);
    gemm1_relu<<<g1, 256, 0, stream>>>(x, W1, b1, h_hid);
    pad_w2<<<(HID_C * PAD_C + 255) / 256, 256, 0, stream>>>(W2, b2, Wp, bp);
    gemm2_tiled<<<(N_NODES + 63) / 64, 256, 0, stream>>>(h_hid, Wp, bp, h0);

    // Propagation x10 (ping-pong; ha/hb reuse h_hid's memory)
    const int prop_blocks = (N_NODES * 64 + 255) / 256;
    const float* cur = h0;
    float* nxt = ha;
    for (int l = 0; l < NUM_LAYERS; ++l) {
        prop_kernel<<<prop_blocks, 256, 0, stream>>>(rowptr, cols_s, ws_s, cur, h0, nxt);
        const float* t = nxt;
        nxt = (nxt == ha) ? hb : ha;
        cur = t;
    }

    // log_softmax
    logsoftmax_kernel<<<prop_blocks, 256, 0, stream>>>(cur, out);
}

// Round 3
// 955.484 us; speedup vs baseline: 2.3448x; 1.1673x over previous
//
#include <hip/hip_runtime.h>
#include <cstddef>
#include <cstdint>
#include <math.h>

#define N_NODES 50000
#define N_EDGES 1600000
#define IN_C 512
#define HID_C 256
#define OUT_C 50
#define PAD_C 64
#define NUM_LAYERS 10
#define NBLK 196          // ceil(50000/256)

typedef __attribute__((ext_vector_type(8))) short short8;    // 8 bf16 (4 VGPRs)
typedef __attribute__((ext_vector_type(4))) float floatx4;   // MFMA C/D frag

__device__ inline unsigned short f2bf(float f) {             // RNE fp32->bf16
    unsigned int u = __float_as_uint(f);
    u += 0x7fffu + ((u >> 16) & 1u);
    return (unsigned short)(u >> 16);
}
__device__ inline float bf2f(unsigned short b) {
    return __uint_as_float(((unsigned int)b) << 16);
}

// ---------------------------------------------------------------------------
// W1 [512,256] fp32  ->  Wt [256,512] bf16   (LDS-tiled transpose)
// ---------------------------------------------------------------------------
__global__ __launch_bounds__(256) void transpose_w1(const float* __restrict__ W1,
                                                    unsigned short* __restrict__ Wt) {
    __shared__ float tile[32][33];
    int bx = blockIdx.x;               // k-tile (16)
    int by = blockIdx.y;               // n-tile (8)
    int tx = threadIdx.x & 31, ty = threadIdx.x >> 5;   // 32 x 8
#pragma unroll
    for (int i = 0; i < 32; i += 8)
        tile[ty + i][tx] = W1[(bx * 32 + ty + i) * HID_C + by * 32 + tx];
    __syncthreads();
#pragma unroll
    for (int i = 0; i < 32; i += 8)
        Wt[(size_t)(by * 32 + ty + i) * IN_C + bx * 32 + tx] = f2bf(tile[tx][ty + i]);
}

// ---------------------------------------------------------------------------
// GEMM1 MFMA: h_hid[M,256] = relu(x[M,512] @ W1 + b1)
// 128x128 tile, BK=32, bf16 MFMA 16x16x32, fp32->bf16 conversion in staging.
// A staged from x (fp32), B staged from Wt (bf16, [n][k]).
// ---------------------------------------------------------------------------
__global__ __launch_bounds__(256) void gemm1_mfma(const float* __restrict__ A,
                                                  const unsigned short* __restrict__ Wt,
                                                  const float* __restrict__ bias,
                                                  float* __restrict__ C) {
    __shared__ unsigned short As[128 * 32];   // [m][k] k-contiguous
    __shared__ unsigned short Bs[128 * 32];   // [n][k] k-contiguous
    const int tid = threadIdx.x;
    const int wave = tid >> 6, lane = tid & 63;
    const int quad = lane >> 4, l16 = lane & 15;
    const int m0 = blockIdx.x * 128, n0 = blockIdx.y * 128;
    const int wm = (wave >> 1) * 64, wn = (wave & 1) * 64;

    floatx4 acc[4][4];
#pragma unroll
    for (int i = 0; i < 4; ++i)
#pragma unroll
        for (int j = 0; j < 4; ++j) acc[i][j] = (floatx4){0.f, 0.f, 0.f, 0.f};

    for (int k0 = 0; k0 < IN_C; k0 += 32) {
        __syncthreads();   // protect previous iteration's reads
        // stage A: 128 rows x 32 k (fp32 -> bf16), 4 chunks/thread
#pragma unroll
        for (int j = 0; j < 4; ++j) {
            int idx = j * 256 + tid;
            int row = idx >> 3, c = idx & 7;
            int gr = m0 + row;
            float4 v = make_float4(0.f, 0.f, 0.f, 0.f);
            if (gr < N_NODES) v = *(const float4*)(A + (size_t)gr * IN_C + k0 + c * 4);
            ushort4 u;
            u.x = f2bf(v.x); u.y = f2bf(v.y); u.z = f2bf(v.z); u.w = f2bf(v.w);
            *(ushort4*)&As[row * 32 + c * 4] = u;
        }
        // stage B: 128 n-rows x 32 k (already bf16)
#pragma unroll
        for (int j = 0; j < 4; ++j) {
            int idx = j * 256 + tid;
            int row = idx >> 3, c = idx & 7;
            ushort4 u = *(const ushort4*)(Wt + (size_t)(n0 + row) * IN_C + k0 + c * 4);
            *(ushort4*)&Bs[row * 32 + c * 4] = u;
        }
        __syncthreads();

        short8 af[4], bf[4];
#pragma unroll
        for (int nt = 0; nt < 4; ++nt)
            bf[nt] = *(const short8*)&Bs[(wn + nt * 16 + l16) * 32 + quad * 8];
#pragma unroll
        for (int mt = 0; mt < 4; ++mt)
            af[mt] = *(const short8*)&As[(wm + mt * 16 + l16) * 32 + quad * 8];
#pragma unroll
        for (int mt = 0; mt < 4; ++mt)
#pragma unroll
            for (int nt = 0; nt < 4; ++nt)
                acc[mt][nt] = __builtin_amdgcn_mfma_f32_16x16x32_bf16(af[mt], bf[nt],
                                                                      acc[mt][nt], 0, 0, 0);
    }

    // epilogue: C[m][n] = relu(acc + bias[n]);  row = quad*4+r, col = l16
#pragma unroll
    for (int nt = 0; nt < 4; ++nt) {
        int n = n0 + wn + nt * 16 + l16;
        float bn = bias[n];
#pragma unroll
        for (int mt = 0; mt < 4; ++mt) {
#pragma unroll
            for (int r = 0; r < 4; ++r) {
                int m = m0 + wm + mt * 16 + quad * 4 + r;
                if (m < N_NODES) {
                    float v = acc[mt][nt][r] + bn;
                    C[(size_t)m * HID_C + n] = v > 0.f ? v : 0.f;
                }
            }
        }
    }
}

// ---------------------------------------------------------------------------
// pad W2 [256,50] -> Wp [256,64] (zeros), b2 -> bp[64]
// ---------------------------------------------------------------------------
__global__ void pad_w2(const float* __restrict__ W2, const float* __restrict__ b2,
                       float* __restrict__ Wp, float* __restrict__ bp) {
    int idx = blockIdx.x * blockDim.x + threadIdx.x;
    if (idx < HID_C * PAD_C) {
        int k = idx >> 6, j = idx & 63;
        Wp[idx] = (j < OUT_C) ? W2[k * OUT_C + j] : 0.f;
    }
    if (idx < PAD_C) bp[idx] = (idx < OUT_C) ? b2[idx] : 0.f;
}

// ---------------------------------------------------------------------------
// GEMM2 tiled: h0 = H[M,256] @ Wp[256,64] + bp ; writes fp32 AND bf16 copies
// ---------------------------------------------------------------------------
__global__ __launch_bounds__(256) void gemm2_tiled(const float* __restrict__ H,
                                                   const float* __restrict__ Wp,
                                                   const float* __restrict__ bp,
                                                   float* __restrict__ h0f,
                                                   unsigned short* __restrict__ h0b) {
    __shared__ float As[16][68];
    __shared__ float Bs[16][64];
    const int tid = threadIdx.x;
    const int tx = tid & 15;
    const int ty = tid >> 4;
    const int m0 = blockIdx.x * 64;

    float acc[4][4];
#pragma unroll
    for (int i = 0; i < 4; ++i)
#pragma unroll
        for (int j = 0; j < 4; ++j) acc[i][j] = 0.f;

    const int arow = tid >> 2;
    const int akk  = (tid & 3) << 2;
    const int brow = tid >> 4;
    const int bcol = (tid & 15) << 2;

    for (int k0 = 0; k0 < HID_C; k0 += 16) {
        float4 av = make_float4(0.f, 0.f, 0.f, 0.f);
        int gr = m0 + arow;
        if (gr < N_NODES)
            av = *(const float4*)(H + (size_t)gr * HID_C + k0 + akk);
        As[akk + 0][arow] = av.x;
        As[akk + 1][arow] = av.y;
        As[akk + 2][arow] = av.z;
        As[akk + 3][arow] = av.w;
        float4 bv = *(const float4*)(Wp + (size_t)(k0 + brow) * PAD_C + bcol);
        *(float4*)&Bs[brow][bcol] = bv;
        __syncthreads();

#pragma unroll
        for (int kk = 0; kk < 16; ++kk) {
            float a[4], b[4];
#pragma unroll
            for (int i = 0; i < 4; ++i) a[i] = As[kk][ty * 4 + i];
#pragma unroll
            for (int j = 0; j < 4; ++j) b[j] = Bs[kk][tx * 4 + j];
#pragma unroll
            for (int i = 0; i < 4; ++i)
#pragma unroll
                for (int j = 0; j < 4; ++j) acc[i][j] = fmaf(a[i], b[j], acc[i][j]);
        }
        __syncthreads();
    }

#pragma unroll
    for (int i = 0; i < 4; ++i) {
        int r = m0 + ty * 4 + i;
        if (r >= N_NODES) continue;
#pragma unroll
        for (int j = 0; j < 4; ++j) {
            int c = tx * 4 + j;
            float v = acc[i][j] + bp[c];
            h0f[(size_t)r * PAD_C + c] = v;
            h0b[(size_t)r * PAD_C + c] = f2bf(v);
        }
    }
}

// ---------------------------------------------------------------------------
// CSR build: histogram + 3-kernel scan + scatter  (unchanged, R2-verified)
// ---------------------------------------------------------------------------
__global__ void hist_kernel(const int* __restrict__ row, int* __restrict__ cnt) {
    int e = blockIdx.x * blockDim.x + threadIdx.x;
    if (e < N_EDGES) atomicAdd(&cnt[row[e]], 1);
}

__global__ __launch_bounds__(256) void scan1(const int* __restrict__ cnt,
                                             int* __restrict__ rowptr,
                                             int* __restrict__ bsum) {
    __shared__ int sd[256];
    int i = blockIdx.x * 256 + threadIdx.x;
    int v = (i < N_NODES) ? cnt[i] : 0;
    sd[threadIdx.x] = v;
    __syncthreads();
    for (int off = 1; off < 256; off <<= 1) {
        int t = (threadIdx.x >= off) ? sd[threadIdx.x - off] : 0;
        __syncthreads();
        sd[threadIdx.x] += t;
        __syncthreads();
    }
    if (i < N_NODES) rowptr[i] = sd[threadIdx.x] - v;
    if (threadIdx.x == 255) bsum[blockIdx.x] = sd[255];
}

__global__ __launch_bounds__(256) void scan2(const int* __restrict__ bsum,
                                             int* __restrict__ boff,
                                             int* __restrict__ total_out) {
    __shared__ int sd[256];
    int v = (threadIdx.x < NBLK) ? bsum[threadIdx.x] : 0;
    sd[threadIdx.x] = v;
    __syncthreads();
    for (int off = 1; off < 256; off <<= 1) {
        int t = (threadIdx.x >= off) ? sd[threadIdx.x - off] : 0;
        __syncthreads();
        sd[threadIdx.x] += t;
        __syncthreads();
    }
    if (threadIdx.x < NBLK) boff[threadIdx.x] = sd[threadIdx.x] - v;
    if (threadIdx.x == 255) total_out[0] = sd[255];
}

__global__ void scan3(int* __restrict__ rowptr, const int* __restrict__ boff) {
    int i = blockIdx.x * blockDim.x + threadIdx.x;
    if (i < N_NODES) rowptr[i] += boff[blockIdx.x];
}

__global__ void scatter_kernel(const int* __restrict__ row, const int* __restrict__ col,
                               const float* __restrict__ w, const int* __restrict__ rowptr,
                               int* __restrict__ fill, int* __restrict__ cols_s,
                               float* __restrict__ ws_s) {
    int e = blockIdx.x * blockDim.x + threadIdx.x;
    if (e >= N_EDGES) return;
    int r = row[e];
    int pos = rowptr[r] + atomicAdd(&fill[r], 1);
    cols_s[pos] = col[e];
    ws_s[pos] = w[e];
}

// ---------------------------------------------------------------------------
// Propagation, bf16 gathers (128 B rows): hout = 0.9*spmm(hin) + 0.1*h0f
// LAST layer writes fp32, others bf16.
// ---------------------------------------------------------------------------
template <bool LAST>
__global__ __launch_bounds__(256) void prop_bf16(const int* __restrict__ rowptr,
                                                 const int* __restrict__ cols,
                                                 const float* __restrict__ wv,
                                                 const unsigned short* __restrict__ hin,
                                                 const float* __restrict__ h0f,
                                                 unsigned short* __restrict__ hout_b,
                                                 float* __restrict__ hout_f) {
    int wave = (blockIdx.x * blockDim.x + threadIdx.x) >> 6;
    int lane = threadIdx.x & 63;
    if (wave >= N_NODES) return;
    int s = rowptr[wave];
    int e = rowptr[wave + 1];
    float a0 = 0.f, a1 = 0.f, a2 = 0.f, a3 = 0.f;
    float a4 = 0.f, a5 = 0.f, a6 = 0.f, a7 = 0.f;
    int i = s;
    for (; i + 8 <= e; i += 8) {
        int s0 = cols[i + 0], s1 = cols[i + 1], s2 = cols[i + 2], s3 = cols[i + 3];
        int s4 = cols[i + 4], s5 = cols[i + 5], s6 = cols[i + 6], s7 = cols[i + 7];
        float w0 = wv[i + 0], w1 = wv[i + 1], w2 = wv[i + 2], w3 = wv[i + 3];
        float w4 = wv[i + 4], w5 = wv[i + 5], w6 = wv[i + 6], w7 = wv[i + 7];
        a0 = fmaf(w0, bf2f(hin[(size_t)s0 * PAD_C + lane]), a0);
        a1 = fmaf(w1, bf2f(hin[(size_t)s1 * PAD_C + lane]), a1);
        a2 = fmaf(w2, bf2f(hin[(size_t)s2 * PAD_C + lane]), a2);
        a3 = fmaf(w3, bf2f(hin[(size_t)s3 * PAD_C + lane]), a3);
        a4 = fmaf(w4, bf2f(hin[(size_t)s4 * PAD_C + lane]), a4);
        a5 = fmaf(w5, bf2f(hin[(size_t)s5 * PAD_C + lane]), a5);
        a6 = fmaf(w6, bf2f(hin[(size_t)s6 * PAD_C + lane]), a6);
        a7 = fmaf(w7, bf2f(hin[(size_t)s7 * PAD_C + lane]), a7);
    }
    for (; i < e; ++i)
        a0 = fmaf(wv[i], bf2f(hin[(size_t)cols[i] * PAD_C + lane]), a0);
    float acc = ((a0 + a1) + (a2 + a3)) + ((a4 + a5) + (a6 + a7));
    size_t o = (size_t)wave * PAD_C + lane;
    float r = 0.9f * acc + 0.1f * h0f[o];
    if (LAST) hout_f[o] = r;
    else      hout_b[o] = f2bf(r);
}

// ---------------------------------------------------------------------------
// log_softmax over 50 channels (fp32 input, stride 64), one wave per node
// ---------------------------------------------------------------------------
__global__ __launch_bounds__(256) void logsoftmax_kernel(const float* __restrict__ h,
                                                         float* __restrict__ out) {
    int wave = (blockIdx.x * blockDim.x + threadIdx.x) >> 6;
    int lane = threadIdx.x & 63;
    if (wave >= N_NODES) return;
    float v = (lane < OUT_C) ? h[(size_t)wave * PAD_C + lane] : -INFINITY;
    float m = v;
#pragma unroll
    for (int off = 32; off; off >>= 1) m = fmaxf(m, __shfl_xor(m, off, 64));
    float p = (lane < OUT_C) ? __expf(v - m) : 0.f;
    float ssum = p;
#pragma unroll
    for (int off = 32; off; off >>= 1) ssum += __shfl_xor(ssum, off, 64);
    if (lane < OUT_C) out[(size_t)wave * OUT_C + lane] = (v - m) - __logf(ssum);
}

// ---------------------------------------------------------------------------
extern "C" void kernel_launch(void* const* d_in, const int* in_sizes, int n_in,
                              void* d_out, int out_size, void* d_ws, size_t ws_size,
                              hipStream_t stream) {
    const float* x    = (const float*)d_in[0];
    const int*   erow = (const int*)d_in[1];
    const int*   ecol = (const int*)d_in[2];
    const float* ew   = (const float*)d_in[3];
    const float* W1   = (const float*)d_in[4];
    const float* b1   = (const float*)d_in[5];
    const float* W2   = (const float*)d_in[6];
    const float* b2   = (const float*)d_in[7];
    float* out = (float*)d_out;

    char* p = (char*)d_ws;
    auto alloc = [&](size_t bytes) {
        char* r = p;
        p += (bytes + 255) & ~(size_t)255;
        return r;
    };
    char*  h_hid_raw = alloc((size_t)N_NODES * HID_C * 4);        // 51.2 MB region
    float* h_hid  = (float*)h_hid_raw;
    float* h0f    = (float*)alloc((size_t)N_NODES * PAD_C * 4);   // 12.8 MB
    unsigned short* h0b = (unsigned short*)alloc((size_t)N_NODES * PAD_C * 2); // 6.4 MB
    int*   cols_s = (int*)alloc((size_t)N_EDGES * 4);
    float* ws_s   = (float*)alloc((size_t)N_EDGES * 4);
    int*   rowptr = (int*)alloc((size_t)(N_NODES + 1) * 4);
    int*   cnt    = (int*)alloc((size_t)N_NODES * 4);
    int*   fill   = (int*)alloc((size_t)N_NODES * 4);
    int*   bsum   = (int*)alloc((size_t)NBLK * 4);
    int*   boff   = (int*)alloc((size_t)NBLK * 4);
    float* Wp     = (float*)alloc((size_t)HID_C * PAD_C * 4);
    float* bp     = (float*)alloc((size_t)PAD_C * 4);
    unsigned short* Wt = (unsigned short*)alloc((size_t)HID_C * IN_C * 2);
    // alias ping-pong + final buffers onto h_hid region (dead after gemm2)
    unsigned short* ha = (unsigned short*)h_hid_raw;                          // 6.4 MB
    unsigned short* hb = (unsigned short*)(h_hid_raw + (size_t)N_NODES * PAD_C * 2); // 6.4 MB
    float* hfinal = (float*)(h_hid_raw + (size_t)N_NODES * PAD_C * 4);        // 12.8 MB

    hipMemsetAsync(cnt, 0, (size_t)N_NODES * 4, stream);
    hipMemsetAsync(fill, 0, (size_t)N_NODES * 4, stream);

    // CSR build
    hist_kernel<<<(N_EDGES + 255) / 256, 256, 0, stream>>>(erow, cnt);
    scan1<<<NBLK, 256, 0, stream>>>(cnt, rowptr, bsum);
    scan2<<<1, 256, 0, stream>>>(bsum, boff, rowptr + N_NODES);
    scan3<<<NBLK, 256, 0, stream>>>(rowptr, boff);
    scatter_kernel<<<(N_EDGES + 255) / 256, 256, 0, stream>>>(erow, ecol, ew, rowptr,
                                                              fill, cols_s, ws_s);

    // MLP
    transpose_w1<<<dim3(IN_C / 32, HID_C / 32), 256, 0, stream>>>(W1, Wt);
    gemm1_mfma<<<dim3((N_NODES + 127) / 128, HID_C / 128), 256, 0, stream>>>(x, Wt, b1, h_hid);
    pad_w2<<<(HID_C * PAD_C + 255) / 256, 256, 0, stream>>>(W2, b2, Wp, bp);
    gemm2_tiled<<<(N_NODES + 63) / 64, 256, 0, stream>>>(h_hid, Wp, bp, h0f, h0b);

    // Propagation x10 (bf16 ping-pong; buffers alias dead h_hid region)
    const int prop_blocks = (N_NODES * 64 + 255) / 256;
    const unsigned short* cur = h0b;
    unsigned short* nxt = ha;
    for (int l = 0; l < NUM_LAYERS - 1; ++l) {
        prop_bf16<false><<<prop_blocks, 256, 0, stream>>>(rowptr, cols_s, ws_s, cur, h0f,
                                                          nxt, nullptr);
        const unsigned short* t = nxt;
        nxt = (nxt == ha) ? hb : ha;
        cur = t;
    }
    prop_bf16<true><<<prop_blocks, 256, 0, stream>>>(rowptr, cols_s, ws_s, cur, h0f,
                                                     nullptr, hfinal);

    // log_softmax
    logsoftmax_kernel<<<prop_blocks, 256, 0, stream>>>(hfinal, out);
}

// Round 4
// 756.604 us; speedup vs baseline: 2.9612x; 1.2629x over previous
//
#include <hip/hip_runtime.h>
#include <cstddef>
#include <cstdint>
#include <math.h>

#define N_NODES 50000
#define N_EDGES 1600000
#define IN_C 512
#define HID_C 256
#define OUT_C 50
#define PAD_C 64
#define NUM_LAYERS 10
#define NBLK 196          // ceil(50000/256)

typedef __attribute__((ext_vector_type(8))) short short8;    // 8 bf16 (4 VGPRs)
typedef __attribute__((ext_vector_type(4))) float floatx4;   // MFMA C/D frag

__device__ inline unsigned short f2bf(float f) {             // RNE fp32->bf16
    unsigned int u = __float_as_uint(f);
    u += 0x7fffu + ((u >> 16) & 1u);
    return (unsigned short)(u >> 16);
}
__device__ inline float bf2f(unsigned short b) {
    return __uint_as_float(((unsigned int)b) << 16);
}

// ---------------------------------------------------------------------------
// W1 [512,256] fp32  ->  Wt [256,512] bf16   (LDS-tiled transpose)
// ---------------------------------------------------------------------------
__global__ __launch_bounds__(256) void transpose_w1(const float* __restrict__ W1,
                                                    unsigned short* __restrict__ Wt) {
    __shared__ float tile[32][33];
    int bx = blockIdx.x;               // k-tile (16)
    int by = blockIdx.y;               // n-tile (8)
    int tx = threadIdx.x & 31, ty = threadIdx.x >> 5;   // 32 x 8
#pragma unroll
    for (int i = 0; i < 32; i += 8)
        tile[ty + i][tx] = W1[(bx * 32 + ty + i) * HID_C + by * 32 + tx];
    __syncthreads();
#pragma unroll
    for (int i = 0; i < 32; i += 8)
        Wt[(size_t)(by * 32 + ty + i) * IN_C + bx * 32 + tx] = f2bf(tile[tx][ty + i]);
}

// ---------------------------------------------------------------------------
// GEMM1 MFMA: h_hid[M,256] = relu(x[M,512] @ W1 + b1)
// 64x128 tile, BK=32, bf16 16x16x32 MFMA, register-prefetch double buffering:
// next K-tile's global loads are issued before the MFMA phase of the current
// tile, so ~400 cyc of ds_read+MFMA hides load latency (R3 was single-
// buffered and stalled the full HBM latency per K-iter: 1.6 TB/s, VALU 8%).
// ---------------------------------------------------------------------------
__global__ __launch_bounds__(256) void gemm1_mfma(const float* __restrict__ A,
                                                  const unsigned short* __restrict__ Wt,
                                                  const float* __restrict__ bias,
                                                  float* __restrict__ C) {
    __shared__ unsigned short As[64 * 32];    // [m][k] k-contiguous
    __shared__ unsigned short Bs[128 * 32];   // [n][k] k-contiguous
    const int tid = threadIdx.x;
    const int wave = tid >> 6, lane = tid & 63;
    const int quad = lane >> 4, l16 = lane & 15;
    const int m0 = blockIdx.x * 64, n0 = blockIdx.y * 128;
    const int wm = (wave >> 1) * 32, wn = (wave & 1) * 64;

    floatx4 acc[2][4];
#pragma unroll
    for (int i = 0; i < 2; ++i)
#pragma unroll
        for (int j = 0; j < 4; ++j) acc[i][j] = (floatx4){0.f, 0.f, 0.f, 0.f};

    // A staging map: idx = j*256+tid (j<2): row = idx>>3 (0..63), c = idx&7
    // B staging map: idx = j*256+tid (j<4): row = idx>>3 (0..127), c = idx&7
    const int a_row = tid >> 3, a_c = tid & 7;           // j folded below
    float4  pa[2];
    ushort4 pb[4];

    auto fetch = [&](int k0) {
#pragma unroll
        for (int j = 0; j < 2; ++j) {
            int row = (j * 256 + tid) >> 3, c = (j * 256 + tid) & 7;
            int gr = m0 + row;
            pa[j] = make_float4(0.f, 0.f, 0.f, 0.f);
            if (gr < N_NODES)
                pa[j] = *(const float4*)(A + (size_t)gr * IN_C + k0 + c * 4);
        }
#pragma unroll
        for (int j = 0; j < 4; ++j) {
            int row = (j * 256 + tid) >> 3, c = (j * 256 + tid) & 7;
            pb[j] = *(const ushort4*)(Wt + (size_t)(n0 + row) * IN_C + k0 + c * 4);
        }
    };

    fetch(0);
    for (int k0 = 0; k0 < IN_C; k0 += 32) {
        __syncthreads();   // previous iteration's ds_reads complete
#pragma unroll
        for (int j = 0; j < 2; ++j) {
            int row = (j * 256 + tid) >> 3, c = (j * 256 + tid) & 7;
            ushort4 u;
            u.x = f2bf(pa[j].x); u.y = f2bf(pa[j].y);
            u.z = f2bf(pa[j].z); u.w = f2bf(pa[j].w);
            *(ushort4*)&As[row * 32 + c * 4] = u;
        }
#pragma unroll
        for (int j = 0; j < 4; ++j) {
            int row = (j * 256 + tid) >> 3, c = (j * 256 + tid) & 7;
            *(ushort4*)&Bs[row * 32 + c * 4] = pb[j];
        }
        __syncthreads();
        if (k0 + 32 < IN_C) fetch(k0 + 32);   // in flight during MFMA phase

        short8 af[2], bf[4];
#pragma unroll
        for (int nt = 0; nt < 4; ++nt)
            bf[nt] = *(const short8*)&Bs[(wn + nt * 16 + l16) * 32 + quad * 8];
#pragma unroll
        for (int mt = 0; mt < 2; ++mt)
            af[mt] = *(const short8*)&As[(wm + mt * 16 + l16) * 32 + quad * 8];
#pragma unroll
        for (int mt = 0; mt < 2; ++mt)
#pragma unroll
            for (int nt = 0; nt < 4; ++nt)
                acc[mt][nt] = __builtin_amdgcn_mfma_f32_16x16x32_bf16(af[mt], bf[nt],
                                                                      acc[mt][nt], 0, 0, 0);
    }
    (void)a_row; (void)a_c;

    // epilogue: row = quad*4+r, col = l16 (R3-verified mapping)
#pragma unroll
    for (int nt = 0; nt < 4; ++nt) {
        int n = n0 + wn + nt * 16 + l16;
        float bn = bias[n];
#pragma unroll
        for (int mt = 0; mt < 2; ++mt) {
#pragma unroll
            for (int r = 0; r < 4; ++r) {
                int m = m0 + wm + mt * 16 + quad * 4 + r;
                if (m < N_NODES) {
                    float v = acc[mt][nt][r] + bn;
                    C[(size_t)m * HID_C + n] = v > 0.f ? v : 0.f;
                }
            }
        }
    }
}

// ---------------------------------------------------------------------------
// pad W2 [256,50] -> Wp [256,64] (zeros), b2 -> bp[64]
// ---------------------------------------------------------------------------
__global__ void pad_w2(const float* __restrict__ W2, const float* __restrict__ b2,
                       float* __restrict__ Wp, float* __restrict__ bp) {
    int idx = blockIdx.x * blockDim.x + threadIdx.x;
    if (idx < HID_C * PAD_C) {
        int k = idx >> 6, j = idx & 63;
        Wp[idx] = (j < OUT_C) ? W2[k * OUT_C + j] : 0.f;
    }
    if (idx < PAD_C) bp[idx] = (idx < OUT_C) ? b2[idx] : 0.f;
}

// ---------------------------------------------------------------------------
// GEMM2 tiled: h0 = H[M,256] @ Wp[256,64] + bp ; writes fp32 AND bf16 copies
// ---------------------------------------------------------------------------
__global__ __launch_bounds__(256) void gemm2_tiled(const float* __restrict__ H,
                                                   const float* __restrict__ Wp,
                                                   const float* __restrict__ bp,
                                                   float* __restrict__ h0f,
                                                   unsigned short* __restrict__ h0b) {
    __shared__ float As[16][68];
    __shared__ float Bs[16][64];
    const int tid = threadIdx.x;
    const int tx = tid & 15;
    const int ty = tid >> 4;
    const int m0 = blockIdx.x * 64;

    float acc[4][4];
#pragma unroll
    for (int i = 0; i < 4; ++i)
#pragma unroll
        for (int j = 0; j < 4; ++j) acc[i][j] = 0.f;

    const int arow = tid >> 2;
    const int akk  = (tid & 3) << 2;
    const int brow = tid >> 4;
    const int bcol = (tid & 15) << 2;

    for (int k0 = 0; k0 < HID_C; k0 += 16) {
        float4 av = make_float4(0.f, 0.f, 0.f, 0.f);
        int gr = m0 + arow;
        if (gr < N_NODES)
            av = *(const float4*)(H + (size_t)gr * HID_C + k0 + akk);
        As[akk + 0][arow] = av.x;
        As[akk + 1][arow] = av.y;
        As[akk + 2][arow] = av.z;
        As[akk + 3][arow] = av.w;
        float4 bv = *(const float4*)(Wp + (size_t)(k0 + brow) * PAD_C + bcol);
        *(float4*)&Bs[brow][bcol] = bv;
        __syncthreads();

#pragma unroll
        for (int kk = 0; kk < 16; ++kk) {
            float a[4], b[4];
#pragma unroll
            for (int i = 0; i < 4; ++i) a[i] = As[kk][ty * 4 + i];
#pragma unroll
            for (int j = 0; j < 4; ++j) b[j] = Bs[kk][tx * 4 + j];
#pragma unroll
            for (int i = 0; i < 4; ++i)
#pragma unroll
                for (int j = 0; j < 4; ++j) acc[i][j] = fmaf(a[i], b[j], acc[i][j]);
        }
        __syncthreads();
    }

#pragma unroll
    for (int i = 0; i < 4; ++i) {
        int r = m0 + ty * 4 + i;
        if (r >= N_NODES) continue;
#pragma unroll
        for (int j = 0; j < 4; ++j) {
            int c = tx * 4 + j;
            float v = acc[i][j] + bp[c];
            h0f[(size_t)r * PAD_C + c] = v;
            h0b[(size_t)r * PAD_C + c] = f2bf(v);
        }
    }
}

// ---------------------------------------------------------------------------
// CSR build: histogram + 3-kernel scan + scatter (packed col+weight)
// ---------------------------------------------------------------------------
__global__ void hist_kernel(const int* __restrict__ row, int* __restrict__ cnt) {
    int e = blockIdx.x * blockDim.x + threadIdx.x;
    if (e < N_EDGES) atomicAdd(&cnt[row[e]], 1);
}

__global__ __launch_bounds__(256) void scan1(const int* __restrict__ cnt,
                                             int* __restrict__ rowptr,
                                             int* __restrict__ bsum) {
    __shared__ int sd[256];
    int i = blockIdx.x * 256 + threadIdx.x;
    int v = (i < N_NODES) ? cnt[i] : 0;
    sd[threadIdx.x] = v;
    __syncthreads();
    for (int off = 1; off < 256; off <<= 1) {
        int t = (threadIdx.x >= off) ? sd[threadIdx.x - off] : 0;
        __syncthreads();
        sd[threadIdx.x] += t;
        __syncthreads();
    }
    if (i < N_NODES) rowptr[i] = sd[threadIdx.x] - v;
    if (threadIdx.x == 255) bsum[blockIdx.x] = sd[255];
}

__global__ __launch_bounds__(256) void scan2(const int* __restrict__ bsum,
                                             int* __restrict__ boff,
                                             int* __restrict__ total_out) {
    __shared__ int sd[256];
    int v = (threadIdx.x < NBLK) ? bsum[threadIdx.x] : 0;
    sd[threadIdx.x] = v;
    __syncthreads();
    for (int off = 1; off < 256; off <<= 1) {
        int t = (threadIdx.x >= off) ? sd[threadIdx.x - off] : 0;
        __syncthreads();
        sd[threadIdx.x] += t;
        __syncthreads();
    }
    if (threadIdx.x < NBLK) boff[threadIdx.x] = sd[threadIdx.x] - v;
    if (threadIdx.x == 255) total_out[0] = sd[255];
}

__global__ void scan3(int* __restrict__ rowptr, const int* __restrict__ boff) {
    int i = blockIdx.x * blockDim.x + threadIdx.x;
    if (i < N_NODES) rowptr[i] += boff[blockIdx.x];
}

__global__ void scatter_kernel(const int* __restrict__ row, const int* __restrict__ col,
                               const float* __restrict__ w, const int* __restrict__ rowptr,
                               int* __restrict__ fill, uint2* __restrict__ edges) {
    int e = blockIdx.x * blockDim.x + threadIdx.x;
    if (e >= N_EDGES) return;
    int r = row[e];
    int pos = rowptr[r] + atomicAdd(&fill[r], 1);
    edges[pos] = make_uint2((unsigned)col[e], __float_as_uint(w[e]));
}

// ---------------------------------------------------------------------------
// Propagation, quartet layout: 16 lanes x 8 B (ushort4 = 4 bf16 channels)
// cover one 128 B row; the 4 lane-quarters process 4 edges per instruction.
// 4x unroll -> 16 edge-rows in flight per wave. Cross-quarter reduction via
// shfl_xor(16/32). hout = 0.9*spmm(hin) + 0.1*h0f; LAST layer writes fp32.
// ---------------------------------------------------------------------------
template <bool LAST>
__global__ __launch_bounds__(256) void prop_quad(const int* __restrict__ rowptr,
                                                 const uint2* __restrict__ edges,
                                                 const unsigned short* __restrict__ hin,
                                                 const float* __restrict__ h0f,
                                                 unsigned short* __restrict__ hout_b,
                                                 float* __restrict__ hout_f) {
    int wid = (blockIdx.x * blockDim.x + threadIdx.x) >> 6;
    if (wid >= N_NODES) return;
    int lane = threadIdx.x & 63;
    int q  = lane >> 4;      // edge slot within quartet
    int lc = lane & 15;      // 8-byte chunk: channels 4lc .. 4lc+3
    int s = rowptr[wid], e = rowptr[wid + 1];

    float a0[4], a1[4], a2[4], a3[4];
#pragma unroll
    for (int j = 0; j < 4; ++j) { a0[j] = 0.f; a1[j] = 0.f; a2[j] = 0.f; a3[j] = 0.f; }

    int i = s;
    for (; i + 16 <= e; i += 16) {
#pragma unroll
        for (int j = 0; j < 4; ++j) {
            uint2 cw = edges[i + 4 * j + q];
            float w = __uint_as_float(cw.y);
            uint2 hv = *(const uint2*)((const char*)hin + ((size_t)cw.x << 7) + lc * 8);
            a0[j] = fmaf(w, __uint_as_float(hv.x << 16),         a0[j]);
            a1[j] = fmaf(w, __uint_as_float(hv.x & 0xffff0000u), a1[j]);
            a2[j] = fmaf(w, __uint_as_float(hv.y << 16),         a2[j]);
            a3[j] = fmaf(w, __uint_as_float(hv.y & 0xffff0000u), a3[j]);
        }
    }
    for (; i < e; i += 4) {   // masked quartet tail
        int idx = i + q;
        uint2 cw = (idx < e) ? edges[idx] : make_uint2(0u, 0u);
        float w = (idx < e) ? __uint_as_float(cw.y) : 0.f;
        uint2 hv = *(const uint2*)((const char*)hin + ((size_t)cw.x << 7) + lc * 8);
        a0[0] = fmaf(w, __uint_as_float(hv.x << 16),         a0[0]);
        a1[0] = fmaf(w, __uint_as_float(hv.x & 0xffff0000u), a1[0]);
        a2[0] = fmaf(w, __uint_as_float(hv.y << 16),         a2[0]);
        a3[0] = fmaf(w, __uint_as_float(hv.y & 0xffff0000u), a3[0]);
    }

    float s0 = (a0[0] + a0[1]) + (a0[2] + a0[3]);
    float s1 = (a1[0] + a1[1]) + (a1[2] + a1[3]);
    float s2 = (a2[0] + a2[1]) + (a2[2] + a2[3]);
    float s3 = (a3[0] + a3[1]) + (a3[2] + a3[3]);
    s0 += __shfl_xor(s0, 16, 64); s0 += __shfl_xor(s0, 32, 64);
    s1 += __shfl_xor(s1, 16, 64); s1 += __shfl_xor(s1, 32, 64);
    s2 += __shfl_xor(s2, 16, 64); s2 += __shfl_xor(s2, 32, 64);
    s3 += __shfl_xor(s3, 16, 64); s3 += __shfl_xor(s3, 32, 64);

    if (q == 0) {
        size_t off = (size_t)wid * PAD_C + lc * 4;
        float4 h0 = *(const float4*)(h0f + off);
        float r0 = 0.9f * s0 + 0.1f * h0.x;
        float r1 = 0.9f * s1 + 0.1f * h0.y;
        float r2 = 0.9f * s2 + 0.1f * h0.z;
        float r3 = 0.9f * s3 + 0.1f * h0.w;
        if (LAST) {
            *(float4*)(hout_f + off) = make_float4(r0, r1, r2, r3);
        } else {
            ushort4 u;
            u.x = f2bf(r0); u.y = f2bf(r1); u.z = f2bf(r2); u.w = f2bf(r3);
            *(ushort4*)(hout_b + off) = u;
        }
    }
}

// ---------------------------------------------------------------------------
// log_softmax over 50 channels (fp32 input, stride 64), one wave per node
// ---------------------------------------------------------------------------
__global__ __launch_bounds__(256) void logsoftmax_kernel(const float* __restrict__ h,
                                                         float* __restrict__ out) {
    int wave = (blockIdx.x * blockDim.x + threadIdx.x) >> 6;
    int lane = threadIdx.x & 63;
    if (wave >= N_NODES) return;
    float v = (lane < OUT_C) ? h[(size_t)wave * PAD_C + lane] : -INFINITY;
    float m = v;
#pragma unroll
    for (int off = 32; off; off >>= 1) m = fmaxf(m, __shfl_xor(m, off, 64));
    float p = (lane < OUT_C) ? __expf(v - m) : 0.f;
    float ssum = p;
#pragma unroll
    for (int off = 32; off; off >>= 1) ssum += __shfl_xor(ssum, off, 64);
    if (lane < OUT_C) out[(size_t)wave * OUT_C + lane] = (v - m) - __logf(ssum);
}

// ---------------------------------------------------------------------------
extern "C" void kernel_launch(void* const* d_in, const int* in_sizes, int n_in,
                              void* d_out, int out_size, void* d_ws, size_t ws_size,
                              hipStream_t stream) {
    const float* x    = (const float*)d_in[0];
    const int*   erow = (const int*)d_in[1];
    const int*   ecol = (const int*)d_in[2];
    const float* ew   = (const float*)d_in[3];
    const float* W1   = (const float*)d_in[4];
    const float* b1   = (const float*)d_in[5];
    const float* W2   = (const float*)d_in[6];
    const float* b2   = (const float*)d_in[7];
    float* out = (float*)d_out;

    char* p = (char*)d_ws;
    auto alloc = [&](size_t bytes) {
        char* r = p;
        p += (bytes + 255) & ~(size_t)255;
        return r;
    };
    char*  h_hid_raw = alloc((size_t)N_NODES * HID_C * 4);        // 51.2 MB region
    float* h_hid  = (float*)h_hid_raw;
    float* h0f    = (float*)alloc((size_t)N_NODES * PAD_C * 4);   // 12.8 MB
    unsigned short* h0b = (unsigned short*)alloc((size_t)N_NODES * PAD_C * 2); // 6.4 MB
    uint2* edges  = (uint2*)alloc((size_t)N_EDGES * 8);           // 12.8 MB packed
    int*   rowptr = (int*)alloc((size_t)(N_NODES + 1) * 4);
    int*   cnt    = (int*)alloc((size_t)N_NODES * 4);
    int*   fill   = (int*)alloc((size_t)N_NODES * 4);
    int*   bsum   = (int*)alloc((size_t)NBLK * 4);
    int*   boff   = (int*)alloc((size_t)NBLK * 4);
    float* Wp     = (float*)alloc((size_t)HID_C * PAD_C * 4);
    float* bp     = (float*)alloc((size_t)PAD_C * 4);
    unsigned short* Wt = (unsigned short*)alloc((size_t)HID_C * IN_C * 2);
    // alias ping-pong + final buffers onto h_hid region (dead after gemm2)
    unsigned short* ha = (unsigned short*)h_hid_raw;                          // 6.4 MB
    unsigned short* hb = (unsigned short*)(h_hid_raw + (size_t)N_NODES * PAD_C * 2); // 6.4 MB
    float* hfinal = (float*)(h_hid_raw + (size_t)N_NODES * PAD_C * 4);        // 12.8 MB

    hipMemsetAsync(cnt, 0, (size_t)N_NODES * 4, stream);
    hipMemsetAsync(fill, 0, (size_t)N_NODES * 4, stream);

    // CSR build
    hist_kernel<<<(N_EDGES + 255) / 256, 256, 0, stream>>>(erow, cnt);
    scan1<<<NBLK, 256, 0, stream>>>(cnt, rowptr, bsum);
    scan2<<<1, 256, 0, stream>>>(bsum, boff, rowptr + N_NODES);
    scan3<<<NBLK, 256, 0, stream>>>(rowptr, boff);
    scatter_kernel<<<(N_EDGES + 255) / 256, 256, 0, stream>>>(erow, ecol, ew, rowptr,
                                                              fill, edges);

    // MLP
    transpose_w1<<<dim3(IN_C / 32, HID_C / 32), 256, 0, stream>>>(W1, Wt);
    gemm1_mfma<<<dim3((N_NODES + 63) / 64, HID_C / 128), 256, 0, stream>>>(x, Wt, b1, h_hid);
    pad_w2<<<(HID_C * PAD_C + 255) / 256, 256, 0, stream>>>(W2, b2, Wp, bp);
    gemm2_tiled<<<(N_NODES + 63) / 64, 256, 0, stream>>>(h_hid, Wp, bp, h0f, h0b);

    // Propagation x10 (bf16 ping-pong; buffers alias dead h_hid region)
    const int prop_blocks = (N_NODES * 64 + 255) / 256;
    const unsigned short* cur = h0b;
    unsigned short* nxt = ha;
    for (int l = 0; l < NUM_LAYERS - 1; ++l) {
        prop_quad<false><<<prop_blocks, 256, 0, stream>>>(rowptr, edges, cur, h0f,
                                                          nxt, nullptr);
        const unsigned short* t = nxt;
        nxt = (nxt == ha) ? hb : ha;
        cur = t;
    }
    prop_quad<true><<<prop_blocks, 256, 0, stream>>>(rowptr, edges, cur, h0f,
                                                     nullptr, hfinal);

    // log_softmax
    logsoftmax_kernel<<<prop_blocks, 256, 0, stream>>>(hfinal, out);
}